// Round 4
// baseline (1600.407 us; speedup 1.0000x reference)
//
#include <hip/hip_runtime.h>
#include <math.h>

// LSTM: B=512, T=1000, I=64, H=50, gates 4H=200 torch order (i,f,g,o).
// One block (256 thr) per batch row, 2 blocks/CU.
// Thread g owns gate row g:
//   - weights pinned in VGPRs via inline-asm global_load (allocator cannot
//     demote asm results; rounds 1-3 all showed C++-level loads get demoted)
//   - x_t loaded through SGPRs (readfirstlane-pinned uniform pointer ->
//     s_load, folded as scalar operand of v_fma: free broadcast)
//   - h broadcast from LDS (single uniform address per read: no conflicts)
// c lives in registers of threads 0..49. Two barriers per step.

#define HSZ 50
#define ISZ 64
#define TSZ 1000
#define GSZ 200

typedef float float4v __attribute__((ext_vector_type(4)));
typedef float float2v __attribute__((ext_vector_type(2)));

__device__ __forceinline__ const float* uniform_ptr(const float* p) {
    unsigned long long u = (unsigned long long)p;
    unsigned lo = __builtin_amdgcn_readfirstlane((unsigned)u);
    unsigned hi = __builtin_amdgcn_readfirstlane((unsigned)(u >> 32));
    return (const float*)(((unsigned long long)hi << 32) | lo);
}

#define LD4(dst, base, OFS) \
    asm volatile("global_load_dwordx4 %0, %1, off offset:" OFS \
                 : "=v"(dst) : "v"(base))
#define LD2(dst, base, OFS) \
    asm volatile("global_load_dwordx2 %0, %1, off offset:" OFS \
                 : "=v"(dst) : "v"(base))

__global__ __launch_bounds__(256, 2) void lstm_fused(
    const float* __restrict__ x,      // [B, T, I]
    const float* __restrict__ W_ih,   // [4H, I]
    const float* __restrict__ W_hh,   // [4H, H]
    const float* __restrict__ b_ih,   // [4H]
    const float* __restrict__ b_hh,   // [4H]
    const float* __restrict__ W_out,  // [2, H]
    const float* __restrict__ b_out,  // [2]
    float* __restrict__ out)          // [B, 2]
{
    const int b   = blockIdx.x;
    const int tid = threadIdx.x;
    const int G   = (tid < GSZ) ? tid : (GSZ - 1);   // clamp: uniform CF

    __shared__ __align__(16) float hs[2][56];  // h double buffer (+pad)
    __shared__ __align__(16) float gs[GSZ];    // activated gates

    // ---- weights pinned in VGPRs via asm (29 loads) ----
    const float* wib = W_ih + (size_t)G * ISZ;   // 256B rows
    const float* whb = W_hh + (size_t)G * HSZ;   // 200B rows (4B aligned)
    float4v wi0, wi1, wi2, wi3, wi4, wi5, wi6, wi7,
            wi8, wi9, wi10, wi11, wi12, wi13, wi14, wi15;
    float4v wh0, wh1, wh2, wh3, wh4, wh5, wh6, wh7, wh8, wh9, wh10, wh11;
    float2v whc;
    LD4(wi0,  wib, "0");   LD4(wi1,  wib, "16");  LD4(wi2,  wib, "32");
    LD4(wi3,  wib, "48");  LD4(wi4,  wib, "64");  LD4(wi5,  wib, "80");
    LD4(wi6,  wib, "96");  LD4(wi7,  wib, "112"); LD4(wi8,  wib, "128");
    LD4(wi9,  wib, "144"); LD4(wi10, wib, "160"); LD4(wi11, wib, "176");
    LD4(wi12, wib, "192"); LD4(wi13, wib, "208"); LD4(wi14, wib, "224");
    LD4(wi15, wib, "240");
    LD4(wh0,  whb, "0");   LD4(wh1,  whb, "16");  LD4(wh2,  whb, "32");
    LD4(wh3,  whb, "48");  LD4(wh4,  whb, "64");  LD4(wh5,  whb, "80");
    LD4(wh6,  whb, "96");  LD4(wh7,  whb, "112"); LD4(wh8,  whb, "128");
    LD4(wh9,  whb, "144"); LD4(wh10, whb, "160"); LD4(wh11, whb, "176");
    LD2(whc,  whb, "192");
    // Wait for all asm loads; threading the regs through the asm forces every
    // later use to see the post-waitcnt definition (no early consumption).
    asm volatile("s_waitcnt vmcnt(0)"
        : "+v"(wi0), "+v"(wi1), "+v"(wi2),  "+v"(wi3),  "+v"(wi4),  "+v"(wi5),
          "+v"(wi6), "+v"(wi7), "+v"(wi8),  "+v"(wi9),  "+v"(wi10), "+v"(wi11),
          "+v"(wi12),"+v"(wi13),"+v"(wi14), "+v"(wi15),
          "+v"(wh0), "+v"(wh1), "+v"(wh2),  "+v"(wh3),  "+v"(wh4),  "+v"(wh5),
          "+v"(wh6), "+v"(wh7), "+v"(wh8),  "+v"(wh9),  "+v"(wh10), "+v"(wh11),
          "+v"(whc)
        :: "memory");

    const float bias = b_ih[G] + b_hh[G];
    // tanh(v) = 2*sigmoid(2v)-1 -> act = s2*sigmoid(s1*v)+s3
    const bool  isg = (G >= 2 * HSZ) && (G < 3 * HSZ);
    const float s1  = isg ? 2.0f : 1.0f;
    const float s2  = s1;
    const float s3  = isg ? -1.0f : 0.0f;

    float c_reg = 0.0f;
    if (tid < 56) { hs[0][tid] = 0.0f; hs[1][tid] = 0.0f; }

    // uniform (SGPR) pointer to this row's x -> s_load broadcasts for free
    const float* xb = uniform_ptr(x + (size_t)b * (TSZ * ISZ));
    __syncthreads();

    for (int t = 0; t < TSZ; ++t) {
        const float* xrow = xb + t * ISZ;       // uniform -> s_load
        const float* hrow = &hs[t & 1][0];

        float a0 = bias, a1 = 0.0f, a2 = 0.0f, a3 = 0.0f;
#define XQ(k, W) { \
        a0 = fmaf(xrow[4*(k)+0], W.x, a0); \
        a1 = fmaf(xrow[4*(k)+1], W.y, a1); \
        a2 = fmaf(xrow[4*(k)+2], W.z, a2); \
        a3 = fmaf(xrow[4*(k)+3], W.w, a3); }
        XQ(0,  wi0)  XQ(1,  wi1)  XQ(2,  wi2)  XQ(3,  wi3)
        XQ(4,  wi4)  XQ(5,  wi5)  XQ(6,  wi6)  XQ(7,  wi7)
        XQ(8,  wi8)  XQ(9,  wi9)  XQ(10, wi10) XQ(11, wi11)
        XQ(12, wi12) XQ(13, wi13) XQ(14, wi14) XQ(15, wi15)
#undef XQ
        const float4v* h4 = (const float4v*)hrow;
#define HQ(k, W) { float4v v = h4[k]; \
        a0 = fmaf(v.x, W.x, a0); a1 = fmaf(v.y, W.y, a1); \
        a2 = fmaf(v.z, W.z, a2); a3 = fmaf(v.w, W.w, a3); }
        HQ(0,  wh0)  HQ(1,  wh1)  HQ(2,  wh2)  HQ(3,  wh3)
        HQ(4,  wh4)  HQ(5,  wh5)  HQ(6,  wh6)  HQ(7,  wh7)
        HQ(8,  wh8)  HQ(9,  wh9)  HQ(10, wh10) HQ(11, wh11)
#undef HQ
        { float2v v = *(const float2v*)(hrow + 48);
          a0 = fmaf(v.x, whc.x, a0); a1 = fmaf(v.y, whc.y, a1); }

        const float acc = (a0 + a1) + (a2 + a3);
        const float u   = s1 * acc;
        const float sig = 1.0f / (1.0f + __expf(-u));
        if (tid < GSZ) gs[tid] = fmaf(s2, sig, s3);
        __syncthreads();                       // gates visible

        if (tid < HSZ) {
            const float ig = gs[tid];
            const float fg = gs[tid + HSZ];
            const float gg = gs[tid + 2 * HSZ];
            const float og = gs[tid + 3 * HSZ];
            c_reg = fmaf(fg, c_reg, ig * gg);
            const float tc = fmaf(2.0f, 1.0f / (1.0f + __expf(-2.0f * c_reg)), -1.0f);
            hs[(t + 1) & 1][tid] = og * tc;
        }
        __syncthreads();                       // new h visible
    }

    // out[b,k] = h_final . W_out[k] + b_out[k]
    if (tid < 2) {
        float acc = b_out[tid];
        const float* wo = W_out + tid * HSZ;
        const float* hf = &hs[TSZ & 1][0];
        #pragma unroll
        for (int j = 0; j < HSZ; ++j) acc = fmaf(hf[j], wo[j], acc);
        out[b * 2 + tid] = acc;
    }
}

extern "C" void kernel_launch(void* const* d_in, const int* in_sizes, int n_in,
                              void* d_out, int out_size, void* d_ws, size_t ws_size,
                              hipStream_t stream) {
    const float* x     = (const float*)d_in[0];
    const float* W_ih  = (const float*)d_in[1];
    const float* W_hh  = (const float*)d_in[2];
    const float* b_ih  = (const float*)d_in[3];
    const float* b_hh  = (const float*)d_in[4];
    const float* W_out = (const float*)d_in[5];
    const float* b_out = (const float*)d_in[6];
    float* out = (float*)d_out;

    const int B = in_sizes[0] / (TSZ * ISZ);   // 512
    hipLaunchKernelGGL(lstm_fused, dim3(B), dim3(256), 0, stream,
                       x, W_ih, W_hh, b_ih, b_hh, W_out, b_out, out);
}

// Round 5
// 1174.857 us; speedup vs baseline: 1.3622x; 1.3622x over previous
//
#include <hip/hip_runtime.h>
#include <math.h>

// LSTM B=512 T=1000 I=64 H=50. Split design:
//  K0: WT[i][g] = W_ih[g][i] transpose (tiny)
//  K1: xg[m][g] = x[m][:]·W_ih[g][:] + b_ih[g] + b_hh[g]   (m = b*1000+t flat)
//      lane = m-row; x-row in regs via LDS stage (stride 65, conflict-free);
//      W via uniform loads (SGPR operand); stores bounced thru LDS (coalesce).
//  K2: recurrence: thread g holds only W_hh row (13 float4, asm-pinned);
//      xg streamed coalesced w/ 4-deep prefetch ring; h LDS-broadcast.
// Fallback (ws too small): round-1 fused kernel (proven, 902 us).

#define HSZ 50
#define ISZ 64
#define TSZ 1000
#define GSZ 200
#define TM  192   // K1 rows per block

typedef float float4v __attribute__((ext_vector_type(4)));
typedef float float2v __attribute__((ext_vector_type(2)));

// ---------------- K0: transpose W_ih ----------------
__global__ void wt_transpose(const float* __restrict__ W_ih,
                             float* __restrict__ WT) {
    int j = blockIdx.x * 256 + threadIdx.x;       // 12800 elems
    if (j < 12800) {
        int i = j / 200, g = j % 200;
        WT[j] = W_ih[g * 64 + i];
    }
}

// ---------------- K1: xg GEMM ----------------
__global__ __launch_bounds__(TM, 2) void xg_gemm(
    const float* __restrict__ x,      // [M][64]
    const float* __restrict__ WT,     // [64][200] (+pad)
    const float* __restrict__ b_ih,
    const float* __restrict__ b_hh,
    float* __restrict__ xg,           // [M][200]
    int M)
{
    __shared__ float xls[TM * 65];
    __shared__ float bounce[TM * 17];
    const int tid = threadIdx.x;
    const long long m0 = (long long)blockIdx.x * TM;

    // stage x rows coalesced -> LDS (stride 65: conflict-free reads)
    const float4* x4 = (const float4*)x;
    #pragma unroll
    for (int p = 0; p < 16; ++p) {
        int fid = tid + p * TM;                   // 0..3071 float4s
        int row = fid >> 4, c4 = fid & 15;
        long long mm = m0 + row;
        float4 v = x4[(mm < M ? mm : 0) * 16 + c4];
        float* d = &xls[row * 65 + c4 * 4];
        d[0] = v.x; d[1] = v.y; d[2] = v.z; d[3] = v.w;
    }
    __syncthreads();

    // per-thread x row -> registers (64 floats; ~95 VGPR total)
    float xr[64];
    #pragma unroll
    for (int i = 0; i < 64; ++i) xr[i] = xls[tid * 65 + i];

    for (int gb = 0; gb < 13; ++gb) {             // g-blocks of 16 (last=8)
        const int g0 = gb * 16;
        float acc[16];
        #pragma unroll
        for (int gg = 0; gg < 16; ++gg) acc[gg] = 0.0f;
        #pragma unroll
        for (int i = 0; i < 64; ++i) {
            const float* wrow = WT + i * 200 + g0;   // uniform -> SGPR operand
            #pragma unroll
            for (int gg = 0; gg < 16; ++gg)
                acc[gg] = fmaf(xr[i], wrow[gg], acc[gg]);
        }
        #pragma unroll
        for (int gg = 0; gg < 16; ++gg)
            acc[gg] += b_ih[g0 + gg] + b_hh[g0 + gg];   // uniform

        __syncthreads();                          // bounce safe to overwrite
        #pragma unroll
        for (int gg = 0; gg < 16; ++gg) bounce[tid * 17 + gg] = acc[gg];
        __syncthreads();

        const int glim = (gb == 12) ? 8 : 16;
        #pragma unroll
        for (int q = 0; q < 4; ++q) {             // coalesced flush
            int f4 = tid + q * TM;                // 0..767
            int tau = f4 >> 2, c = f4 & 3;
            long long mm = m0 + tau;
            if (mm < M && c * 4 < glim) {
                const float* s = &bounce[tau * 17 + c * 4];
                float4 v; v.x = s[0]; v.y = s[1]; v.z = s[2]; v.w = s[3];
                *(float4*)(xg + mm * 200 + g0 + c * 4) = v;
            }
        }
    }
}

// ---------------- K2: recurrence ----------------
#define LD4(dst, base, OFS) \
    asm volatile("global_load_dwordx4 %0, %1, off offset:" OFS \
                 : "=v"(dst) : "v"(base))
#define LD2(dst, base, OFS) \
    asm volatile("global_load_dwordx2 %0, %1, off offset:" OFS \
                 : "=v"(dst) : "v"(base))

__global__ __launch_bounds__(256, 2) void lstm_rec(
    const float* __restrict__ xg,     // [M][200] biases folded
    const float* __restrict__ W_hh,   // [200][50]
    const float* __restrict__ W_out,
    const float* __restrict__ b_out,
    float* __restrict__ out)
{
    const int b   = blockIdx.x;
    const int tid = threadIdx.x;
    const int G   = (tid < GSZ) ? tid : (GSZ - 1);

    __shared__ __align__(16) float hs[2][56];
    __shared__ __align__(16) float gs[GSZ];

    // W_hh row pinned: 13 regs = 52 floats (well under allocator's ~100 limit)
    const float* whb = W_hh + (size_t)G * HSZ;
    float4v wh0, wh1, wh2, wh3, wh4, wh5, wh6, wh7, wh8, wh9, wh10, wh11;
    float2v whc;
    LD4(wh0, whb, "0");   LD4(wh1, whb, "16");  LD4(wh2,  whb, "32");
    LD4(wh3, whb, "48");  LD4(wh4, whb, "64");  LD4(wh5,  whb, "80");
    LD4(wh6, whb, "96");  LD4(wh7, whb, "112"); LD4(wh8,  whb, "128");
    LD4(wh9, whb, "144"); LD4(wh10, whb, "160"); LD4(wh11, whb, "176");
    LD2(whc, whb, "192");
    asm volatile("s_waitcnt vmcnt(0)"
        : "+v"(wh0), "+v"(wh1), "+v"(wh2), "+v"(wh3), "+v"(wh4), "+v"(wh5),
          "+v"(wh6), "+v"(wh7), "+v"(wh8), "+v"(wh9), "+v"(wh10), "+v"(wh11),
          "+v"(whc)
        :: "memory");

    const bool  isg = (G >= 2 * HSZ) && (G < 3 * HSZ);
    const float s1  = isg ? 2.0f : 1.0f;
    const float s2  = s1;
    const float s3  = isg ? -1.0f : 0.0f;

    float c_reg = 0.0f;
    if (tid < 56) { hs[0][tid] = 0.0f; hs[1][tid] = 0.0f; }

    const float* xgb = xg + (long long)b * TSZ * GSZ + G;  // per-thread column

    // 4-deep prefetch ring
    float p0 = xgb[0 * GSZ], p1 = xgb[1 * GSZ],
          p2 = xgb[2 * GSZ], p3 = xgb[3 * GSZ];
    __syncthreads();

#define STEP(P, T) {                                                        \
        float a0 = (P), a1 = 0.0f, a2 = 0.0f, a3 = 0.0f;                    \
        {   int tp = (T) + 4; if (tp > TSZ - 1) tp = 0;                     \
            (P) = xgb[tp * GSZ]; }                                          \
        const float* hrow = &hs[(T) & 1][0];                                \
        const float4v* h4 = (const float4v*)hrow;                           \
        { float4v v = h4[0];  a0 = fmaf(v.x, wh0.x, a0);  a1 = fmaf(v.y, wh0.y, a1);  a2 = fmaf(v.z, wh0.z, a2);  a3 = fmaf(v.w, wh0.w, a3); } \
        { float4v v = h4[1];  a0 = fmaf(v.x, wh1.x, a0);  a1 = fmaf(v.y, wh1.y, a1);  a2 = fmaf(v.z, wh1.z, a2);  a3 = fmaf(v.w, wh1.w, a3); } \
        { float4v v = h4[2];  a0 = fmaf(v.x, wh2.x, a0);  a1 = fmaf(v.y, wh2.y, a1);  a2 = fmaf(v.z, wh2.z, a2);  a3 = fmaf(v.w, wh2.w, a3); } \
        { float4v v = h4[3];  a0 = fmaf(v.x, wh3.x, a0);  a1 = fmaf(v.y, wh3.y, a1);  a2 = fmaf(v.z, wh3.z, a2);  a3 = fmaf(v.w, wh3.w, a3); } \
        { float4v v = h4[4];  a0 = fmaf(v.x, wh4.x, a0);  a1 = fmaf(v.y, wh4.y, a1);  a2 = fmaf(v.z, wh4.z, a2);  a3 = fmaf(v.w, wh4.w, a3); } \
        { float4v v = h4[5];  a0 = fmaf(v.x, wh5.x, a0);  a1 = fmaf(v.y, wh5.y, a1);  a2 = fmaf(v.z, wh5.z, a2);  a3 = fmaf(v.w, wh5.w, a3); } \
        { float4v v = h4[6];  a0 = fmaf(v.x, wh6.x, a0);  a1 = fmaf(v.y, wh6.y, a1);  a2 = fmaf(v.z, wh6.z, a2);  a3 = fmaf(v.w, wh6.w, a3); } \
        { float4v v = h4[7];  a0 = fmaf(v.x, wh7.x, a0);  a1 = fmaf(v.y, wh7.y, a1);  a2 = fmaf(v.z, wh7.z, a2);  a3 = fmaf(v.w, wh7.w, a3); } \
        { float4v v = h4[8];  a0 = fmaf(v.x, wh8.x, a0);  a1 = fmaf(v.y, wh8.y, a1);  a2 = fmaf(v.z, wh8.z, a2);  a3 = fmaf(v.w, wh8.w, a3); } \
        { float4v v = h4[9];  a0 = fmaf(v.x, wh9.x, a0);  a1 = fmaf(v.y, wh9.y, a1);  a2 = fmaf(v.z, wh9.z, a2);  a3 = fmaf(v.w, wh9.w, a3); } \
        { float4v v = h4[10]; a0 = fmaf(v.x, wh10.x, a0); a1 = fmaf(v.y, wh10.y, a1); a2 = fmaf(v.z, wh10.z, a2); a3 = fmaf(v.w, wh10.w, a3); } \
        { float4v v = h4[11]; a0 = fmaf(v.x, wh11.x, a0); a1 = fmaf(v.y, wh11.y, a1); a2 = fmaf(v.z, wh11.z, a2); a3 = fmaf(v.w, wh11.w, a3); } \
        { float2v v = *(const float2v*)(hrow + 48);                         \
          a0 = fmaf(v.x, whc.x, a0); a1 = fmaf(v.y, whc.y, a1); }           \
        const float accv = (a0 + a1) + (a2 + a3);                           \
        const float sig  = 1.0f / (1.0f + __expf(-s1 * accv));              \
        if (tid < GSZ) gs[tid] = fmaf(s2, sig, s3);                         \
        __syncthreads();                                                    \
        if (tid < HSZ) {                                                    \
            const float ig = gs[tid];                                       \
            const float fg = gs[tid + HSZ];                                 \
            const float gg = gs[tid + 2 * HSZ];                             \
            const float og = gs[tid + 3 * HSZ];                             \
            c_reg = fmaf(fg, c_reg, ig * gg);                               \
            const float tc = fmaf(2.0f, 1.0f / (1.0f + __expf(-2.0f * c_reg)), -1.0f); \
            hs[((T) + 1) & 1][tid] = og * tc;                               \
        }                                                                   \
        __syncthreads(); }

    for (int t = 0; t < TSZ; t += 4) {
        STEP(p0, t)
        STEP(p1, t + 1)
        STEP(p2, t + 2)
        STEP(p3, t + 3)
    }
#undef STEP

    if (tid < 2) {
        float acc = b_out[tid];
        const float* wo = W_out + tid * HSZ;
        const float* hf = &hs[0][0];              // 1000 & 1 == 0
        #pragma unroll
        for (int j = 0; j < HSZ; ++j) acc = fmaf(hf[j], wo[j], acc);
        out[b * 2 + tid] = acc;
    }
}

// ---------------- Fallback: round-1 fused kernel (proven) ----------------
__global__ __launch_bounds__(256, 2) void lstm_fallback(
    const float* __restrict__ x, const float* __restrict__ W_ih,
    const float* __restrict__ W_hh, const float* __restrict__ b_ih,
    const float* __restrict__ b_hh, const float* __restrict__ W_out,
    const float* __restrict__ b_out, float* __restrict__ out)
{
    const int b = blockIdx.x, tid = threadIdx.x;
    __shared__ __align__(16) float xs[2][ISZ];
    __shared__ __align__(16) float hs[HSZ + 2];
    __shared__ __align__(16) float gs[GSZ];
    float wih[ISZ]; float whh[HSZ]; float bias = 0.0f;
    if (tid < GSZ) {
        const float* wi = W_ih + tid * ISZ;
        #pragma unroll
        for (int i = 0; i < ISZ; ++i) wih[i] = wi[i];
        const float* wh = W_hh + tid * HSZ;
        #pragma unroll
        for (int j = 0; j < HSZ; ++j) whh[j] = wh[j];
        bias = b_ih[tid] + b_hh[tid];
    }
    float c_reg = 0.0f;
    if (tid < HSZ) hs[tid] = 0.0f;
    const float* xb = x + (size_t)b * (TSZ * ISZ);
    if (tid < ISZ) xs[0][tid] = xb[tid];
    __syncthreads();
    for (int t = 0; t < TSZ; ++t) {
        const int cur = t & 1, nxt = cur ^ 1;
        float xpre = 0.0f;
        const bool pf = (t + 1 < TSZ) && (tid < ISZ);
        if (pf) xpre = xb[(size_t)(t + 1) * ISZ + tid];
        if (tid < GSZ) {
            float acc = bias;
            const float4* x4 = (const float4*)(&xs[cur][0]);
            #pragma unroll
            for (int i = 0; i < ISZ / 4; ++i) {
                float4 v = x4[i];
                acc += v.x * wih[4*i] + v.y * wih[4*i+1] + v.z * wih[4*i+2] + v.w * wih[4*i+3];
            }
            const float4* h4 = (const float4*)(&hs[0]);
            #pragma unroll
            for (int j = 0; j < 12; ++j) {
                float4 v = h4[j];
                acc += v.x * whh[4*j] + v.y * whh[4*j+1] + v.z * whh[4*j+2] + v.w * whh[4*j+3];
            }
            acc += hs[48] * whh[48] + hs[49] * whh[49];
            float a = (tid >= 2*HSZ && tid < 3*HSZ)
                ? (1.0f - 2.0f / (1.0f + __expf(2.0f * acc)))
                : (1.0f / (1.0f + __expf(-acc)));
            gs[tid] = a;
        }
        if (pf) xs[nxt][tid] = xpre;
        __syncthreads();
        if (tid < HSZ) {
            float ig = gs[tid], fg = gs[tid+HSZ], gg = gs[tid+2*HSZ], og = gs[tid+3*HSZ];
            c_reg = fg * c_reg + ig * gg;
            hs[tid] = og * (1.0f - 2.0f / (1.0f + __expf(2.0f * c_reg)));
        }
        __syncthreads();
    }
    if (tid < 2) {
        float acc = b_out[tid];
        const float* wo = W_out + tid * HSZ;
        #pragma unroll
        for (int j = 0; j < HSZ; ++j) acc = fmaf(hs[j], wo[j], acc);
        out[b * 2 + tid] = acc;
    }
}

extern "C" void kernel_launch(void* const* d_in, const int* in_sizes, int n_in,
                              void* d_out, int out_size, void* d_ws, size_t ws_size,
                              hipStream_t stream) {
    const float* x     = (const float*)d_in[0];
    const float* W_ih  = (const float*)d_in[1];
    const float* W_hh  = (const float*)d_in[2];
    const float* b_ih  = (const float*)d_in[3];
    const float* b_hh  = (const float*)d_in[4];
    const float* W_out = (const float*)d_in[5];
    const float* b_out = (const float*)d_in[6];
    float* out = (float*)d_out;

    const int B = in_sizes[0] / (TSZ * ISZ);        // 512
    const int M = B * TSZ;                          // 512000
    const size_t xg_bytes = (size_t)M * GSZ * 4;    // 409.6 MB
    const size_t need = xg_bytes + 12864 * 4;       // + WT (padded)

    if (ws_size >= need) {
        float* xg = (float*)d_ws;
        float* WT = (float*)((char*)d_ws + xg_bytes);
        hipLaunchKernelGGL(wt_transpose, dim3(50), dim3(256), 0, stream, W_ih, WT);
        const int nblk = (M + TM - 1) / TM;
        hipLaunchKernelGGL(xg_gemm, dim3(nblk), dim3(TM), 0, stream,
                           x, WT, b_ih, b_hh, xg, M);
        hipLaunchKernelGGL(lstm_rec, dim3(B), dim3(256), 0, stream,
                           xg, W_hh, W_out, b_out, out);
    } else {
        hipLaunchKernelGGL(lstm_fallback, dim3(B), dim3(256), 0, stream,
                           x, W_ih, W_hh, b_ih, b_hh, W_out, b_out, out);
    }
}